// Round 2
// baseline (735.765 us; speedup 1.0000x reference)
//
#include <hip/hip_runtime.h>
#include <hip/hip_fp16.h>

// Problem constants
#define NCLS 512
#define COUT 256
#define BB 4
#define TT 16
#define HH 64
#define WW 64

static constexpr size_t TABLE_ELEMS = 27ull * NCLS * COUT;   // half elements
static constexpr size_t TABLE_BYTES = TABLE_ELEMS * sizeof(__half);

typedef float  f4 __attribute__((ext_vector_type(4)));
typedef float  f2 __attribute__((ext_vector_type(2)));

// ---------------------------------------------------------------------------
// Kernel 1: repack weight (C=256, N=512, 27) fp32  ->  table[27][512][256] half
// Nontemporal reads: the 56 MB fp32 weight is touched once and must not evict
// the table from L2.
// ---------------------------------------------------------------------------
__global__ __launch_bounds__(256) void repack_kernel(const float* __restrict__ w,
                                                     __half* __restrict__ tbl) {
    int n = blockIdx.x;     // 0..511
    int c = threadIdx.x;    // 0..255
    const float* src = w + ((size_t)c * NCLS + n) * 27;
    float v[27];
#pragma unroll
    for (int k = 0; k < 27; ++k) v[k] = __builtin_nontemporal_load(src + k);
#pragma unroll
    for (int k = 0; k < 27; ++k)
        tbl[((size_t)k * NCLS + n) * COUT + c] = __float2half(v[k]);
}

// ---------------------------------------------------------------------------
// Kernel 2: gather-accumulate, channel-split for per-XCD L2 residency.
// Grid = 8192 blocks: blockIdx = pos*2 + half. half selects channels
// [half*128, half*128+128) -> per-XCD table slice 3.375 MiB < 4 MiB L2.
// With round-robin blockIdx->XCD dispatch, even XCDs see only half 0 and odd
// XCDs only half 1 (perf heuristic; correctness never depends on it).
// Lane covers 2 channels (one dword gather per tap = 256 B coalesced row).
// All 27 gathers preloaded to registers before accumulation (MLP), two
// accumulators break the v_pk_add_f16 dependency chain. Output transposed
// through LDS, stored with nontemporal float4 (no L2 write-allocate).
// ---------------------------------------------------------------------------
__global__ __launch_bounds__(256) void conv_kernel(const int* __restrict__ idx,
                                                   const __half* __restrict__ tbl,
                                                   const float* __restrict__ bias,
                                                   float* __restrict__ out) {
    __shared__ int soff[3 * 3 * 66];      // clamped index offsets (n << 8)
    __shared__ float tile[16 * 128];      // [w16][c_local] staging, 8 KB

    int g = blockIdx.x;
    int half = g & 1;
    int pos = g >> 1;                     // b*1024 + t*64 + h
    int h = pos & 63;
    int t = (pos >> 6) & 15;
    int b = pos >> 10;
    int tid = threadIdx.x;

    // ---- stage clamped indices for the (3 dt) x (3 dh) x (66 w) window
    for (int e = tid; e < 594; e += 256) {
        int tt = e / 198;
        int r  = e - tt * 198;
        int hh = r / 66;
        int ww = r - hh * 66;
        int ts = t + tt - 2; if (ts < 0) ts = 0;                 // edge pad (2,0)
        int hs = h + hh - 1; if (hs < 0) hs = 0; if (hs > 63) hs = 63;
        int ws = ww - 1;     if (ws < 0) ws = 0; if (ws > 63) ws = 63;
        int n = idx[(((b * TT + ts) * HH) + hs) * WW + ws];
        soff[e] = n << 8;                                        // n * 256 elems
    }
    __syncthreads();

    int lane = tid & 63;
    int wave = tid >> 6;
    int c2 = (half << 7) + (lane << 1);   // this lane's 2 channels (global)
    const __half* tb = tbl + c2;

    for (int chunk = 0; chunk < 4; ++chunk) {
        // each wave computes 4 w positions of this 16-w chunk
#pragma unroll
        for (int j = 0; j < 4; ++j) {
            int w16 = (wave << 2) + j;
            int w = (chunk << 4) + w16;

            unsigned v[27];
#pragma unroll
            for (int kt = 0; kt < 9; ++kt) {          // kt = dt*3 + dh
                int base = kt * 66 + w;
#pragma unroll
                for (int dw = 0; dw < 3; ++dw) {
                    int k = kt * 3 + dw;
                    v[k] = *reinterpret_cast<const unsigned*>(
                        tb + (size_t)k * (NCLS * COUT) + soff[base + dw]);
                }
            }
            __half2 a0 = __float2half2_rn(0.0f);
            __half2 a1 = __float2half2_rn(0.0f);
#pragma unroll
            for (int k = 0; k + 1 < 27; k += 2) {
                a0 = __hadd2(a0, *reinterpret_cast<__half2*>(&v[k]));
                a1 = __hadd2(a1, *reinterpret_cast<__half2*>(&v[k + 1]));
            }
            a0 = __hadd2(a0, *reinterpret_cast<__half2*>(&v[26]));
            a0 = __hadd2(a0, a1);

            float2 f = __half22float2(a0);
            *reinterpret_cast<f2*>(&tile[w16 * 128 + (lane << 1)]) = f2{f.x, f.y};
        }
        __syncthreads();

        // ---- store phase: 256 threads cover 128 channels x 2 w-halves
        {
            int cl = tid & 127;           // local channel
            int part = tid >> 7;          // which 8-w half of the chunk
            int cg = (half << 7) + cl;
            float bv = bias[cg];
            float* obase = out + ((((size_t)b * COUT + cg) * TT + t) * HH + h) * WW
                               + (chunk << 4) + (part << 3);
#pragma unroll
            for (int q = 0; q < 2; ++q) {
                int wb = (part << 3) + (q << 2);
                f4 vv = { tile[(wb + 0) * 128 + cl] + bv,
                          tile[(wb + 1) * 128 + cl] + bv,
                          tile[(wb + 2) * 128 + cl] + bv,
                          tile[(wb + 3) * 128 + cl] + bv };
                __builtin_nontemporal_store(vv, reinterpret_cast<f4*>(obase + (q << 2)));
            }
        }
        __syncthreads();
    }
}

extern "C" void kernel_launch(void* const* d_in, const int* in_sizes, int n_in,
                              void* d_out, int out_size, void* d_ws, size_t ws_size,
                              hipStream_t stream) {
    const int*   indices = (const int*)d_in[0];
    const float* weight  = (const float*)d_in[1];
    const float* bias    = (const float*)d_in[2];
    float*       out     = (float*)d_out;

    __half* tbl = (__half*)d_ws;
    repack_kernel<<<NCLS, 256, 0, stream>>>(weight, tbl);
    conv_kernel<<<BB * TT * HH * 2, 256, 0, stream>>>(indices, tbl, bias, out);
}